// Round 2
// baseline (279.508 us; speedup 1.0000x reference)
//
#include <hip/hip_runtime.h>
#include <hip/hip_bf16.h>

#define BB 128
#define NN 2048
#define DD 128
#define HH 8

// ws layout (float offsets)
#define GSUM_OFF 0            // B*D = 16384 floats (zeroed)
#define ESUM_OFF 16384        // B*H = 1024 floats (zeroed)
#define WQE_OFF  17408        // B*H*D = 131072 floats
#define SB_OFF   148480       // B*H = 1024 floats
#define E_OFF    262144       // B*H*N = 2097152 floats (8 MB)

// K1: gsum[b][d] = sum_n x[b][n][d]
__global__ void k1_gsum(const float* __restrict__ x, float* __restrict__ gsum) {
    int b = blockIdx.y;
    int chunk = blockIdx.x;      // 16 chunks of 128 rows
    int t = threadIdx.x;         // 128 threads
    int c2 = t & 63;             // float2 column
    int rg = t >> 6;             // row parity
    const float2* x2 = (const float2*)(x + ((size_t)b * NN + chunk * 128) * DD);
    float2 acc = make_float2(0.f, 0.f);
    for (int i = 0; i < 64; ++i) {
        float2 v = x2[(size_t)(rg + 2 * i) * 64 + c2];
        acc.x += v.x; acc.y += v.y;
    }
    atomicAdd(&gsum[b * DD + c2 * 2 + 0], acc.x);
    atomicAdd(&gsum[b * DD + c2 * 2 + 1], acc.y);
}

// K2: per batch: context -> q_in -> q -> wq_eff (scaled by 0.25), sb
__global__ void k2_q(const float* __restrict__ x,
                     const int* __restrict__ fn_p, const int* __restrict__ cn_p,
                     const float* __restrict__ Wl, const float* __restrict__ bl,
                     const float* __restrict__ Wq, const float* __restrict__ bq,
                     const float* __restrict__ Wk, const float* __restrict__ bk,
                     float* __restrict__ ws) {
    __shared__ float ctx[384];
    __shared__ float qin[128];
    __shared__ float qv[128];
    int b = blockIdx.x, t = threadIdx.x;

    // int64 vs int32 layout hedge: int64-LE arrays (values < 2^31) have all odd 32-bit words == 0
    bool is64 = (fn_p[1] == 0 && fn_p[3] == 0 && fn_p[5] == 0 && fn_p[7] == 0 &&
                 cn_p[1] == 0 && cn_p[3] == 0 && cn_p[5] == 0 && cn_p[7] == 0);
    int fn = is64 ? fn_p[2 * b] : fn_p[b];
    int cn = is64 ? cn_p[2 * b] : cn_p[b];

    const float* gsum = ws + GSUM_OFF;
    ctx[t]       = gsum[b * DD + t] * (1.0f / NN);
    ctx[128 + t] = x[((size_t)b * NN + fn) * DD + t];
    ctx[256 + t] = x[((size_t)b * NN + cn) * DD + t];
    __syncthreads();

    float a = bl[t];
    const float* wrow = Wl + (size_t)t * 384;
    for (int e = 0; e < 384; ++e) a += ctx[e] * wrow[e];
    qin[t] = a;
    __syncthreads();

    float a2 = bq[t];
    const float* wrow2 = Wq + (size_t)t * 128;
    for (int e = 0; e < 128; ++e) a2 += qin[e] * wrow2[e];
    qv[t] = a2;
    __syncthreads();

    float* wqe = ws + WQE_OFF + (size_t)b * HH * DD;
    for (int h = 0; h < HH; ++h) {
        float w = 0.f;
        for (int j = 0; j < 16; ++j) w += qv[h * 16 + j] * Wk[(size_t)(h * 16 + j) * 128 + t];
        wqe[h * DD + t] = 0.25f * w;
    }
    if (t < HH) {
        float s = 0.f;
        for (int j = 0; j < 16; ++j) s += qv[t * 16 + j] * bk[t * 16 + j];
        (ws + SB_OFF)[b * HH + t] = 0.25f * s;
    }
}

// mask layout: 0 = byte (np.bool_), 1 = int32, 2 = int64
__device__ __forceinline__ int detect_mask_kind(const int* mw) {
    int big = 0, oddnz = 0;
    #pragma unroll 8
    for (int i = 0; i < 64; ++i) {
        unsigned w = (unsigned)mw[i];
        if (w > 1u) big = 1;
        if ((i & 1) && w != 0u) oddnz = 1;
    }
    return big ? 0 : (oddnz ? 1 : 2);
}

__device__ __forceinline__ int mask_at(const unsigned char* mb, const int* mw, int kind, size_t idx) {
    if (kind == 0) return mb[idx];
    if (kind == 1) return mw[idx];
    return mw[2 * idx];
}

// K3: e[b][h][n] = mask ? 0 : exp(score); partial sums -> esum (atomic)
__launch_bounds__(256)
__global__ void k3_exp(const float* __restrict__ x, const void* __restrict__ mask,
                       const float* __restrict__ ws_ro,
                       float* __restrict__ wse, float* __restrict__ esum) {
    __shared__ float xs[64 * 132];   // padded stride 132 -> conflict-free
    __shared__ float wqs[8 * 132];
    __shared__ float sbs[8];
    int b = blockIdx.y, cx = blockIdx.x, t = threadIdx.x;

    const unsigned char* mb = (const unsigned char*)mask;
    const int* mw = (const int*)mask;
    int mkind = detect_mask_kind(mw);

    const float* wqe = ws_ro + WQE_OFF + (size_t)b * HH * DD;
    for (int i = t; i < 1024; i += 256) wqs[(i >> 7) * 132 + (i & 127)] = wqe[i];
    if (t < 8) sbs[t] = (ws_ro + SB_OFF)[b * HH + t];

    int h = t >> 5, nl = t & 31;
    float myes = 0.f;
    const float4* wrow = (const float4*)&wqs[h * 132];

    for (int sc = 0; sc < 4; ++sc) {
        int nb = cx * 256 + sc * 64;
        __syncthreads();  // xs free to overwrite (also covers wqs staging on sc==0)
        const float4* xsrc = (const float4*)(x + ((size_t)b * NN + nb) * DD);
        for (int i = 0; i < 8; ++i) {
            int f4 = t + i * 256;
            int r = f4 >> 5, c4 = f4 & 31;
            *(float4*)&xs[r * 132 + c4 * 4] = xsrc[f4];
        }
        __syncthreads();

        float acc0 = sbs[h], acc1 = sbs[h];
        const float4* xr0 = (const float4*)&xs[nl * 132];
        const float4* xr1 = (const float4*)&xs[(nl + 32) * 132];
        #pragma unroll
        for (int e4 = 0; e4 < 32; ++e4) {
            float4 w = wrow[e4];
            float4 a = xr0[e4];
            float4 c = xr1[e4];
            acc0 += a.x * w.x + a.y * w.y + a.z * w.z + a.w * w.w;
            acc1 += c.x * w.x + c.y * w.y + c.z * w.z + c.w * w.w;
        }
        int n0 = nb + nl, n1 = nb + nl + 32;
        float e0 = mask_at(mb, mw, mkind, (size_t)b * NN + n0) ? 0.f : __expf(acc0);
        float e1 = mask_at(mb, mw, mkind, (size_t)b * NN + n1) ? 0.f : __expf(acc1);
        wse[((size_t)(b * HH + h)) * NN + n0] = e0;
        wse[((size_t)(b * HH + h)) * NN + n1] = e1;
        myes += e0 + e1;
    }
    // reduce over the 32 lanes sharing h
    for (int off = 16; off >= 1; off >>= 1) myes += __shfl_xor(myes, off, 64);
    if (nl == 0) atomicAdd(&esum[b * HH + h], myes);
}

// K4: out[b][n] = sum_h e[b][h][n] * (0.125 / esum[b][h])
__global__ void k4_out(const float* __restrict__ wse, const float* __restrict__ esum,
                       float* __restrict__ out) {
    __shared__ float rinv[8];
    int b = blockIdx.y, cx = blockIdx.x, t = threadIdx.x;
    if (t < 8) rinv[t] = 0.125f / esum[b * HH + t];
    __syncthreads();
    int n = cx * 256 + t;
    float o = 0.f;
    #pragma unroll
    for (int h = 0; h < HH; ++h)
        o += wse[((size_t)(b * HH + h)) * NN + n] * rinv[h];
    out[(size_t)b * NN + n] = o;
}

extern "C" void kernel_launch(void* const* d_in, const int* in_sizes, int n_in,
                              void* d_out, int out_size, void* d_ws, size_t ws_size,
                              hipStream_t stream) {
    const float* x  = (const float*)d_in[0];
    const int* fn   = (const int*)d_in[1];
    const int* cn   = (const int*)d_in[2];
    const void* mk  = d_in[3];
    const float* Wl = (const float*)d_in[4];
    const float* bl = (const float*)d_in[5];
    const float* Wq = (const float*)d_in[6];
    const float* bq = (const float*)d_in[7];
    const float* Wk = (const float*)d_in[8];
    const float* bk = (const float*)d_in[9];
    float* ws  = (float*)d_ws;
    float* out = (float*)d_out;

    // zero gsum + esum accumulators (ws is poisoned 0xAA before every launch)
    hipMemsetAsync(d_ws, 0, (size_t)(16384 + 1024) * 4, stream);

    k1_gsum<<<dim3(16, BB), 128, 0, stream>>>(x, ws + GSUM_OFF);
    k2_q<<<BB, 128, 0, stream>>>(x, fn, cn, Wl, bl, Wq, bq, Wk, bk, ws);
    k3_exp<<<dim3(8, BB), 256, 0, stream>>>(x, mk, ws, ws + E_OFF, ws + ESUM_OFF);
    k4_out<<<dim3(8, BB), 256, 0, stream>>>(ws + E_OFF, ws + ESUM_OFF, out);
}